// Round 6
// baseline (2049.768 us; speedup 1.0000x reference)
//
#include <hip/hip_runtime.h>
#include <math.h>

// Problem constants
#define L_LAYERS 4
#define B_G 128
#define S_G 128
#define N_N 16384      // B*S
#define E_E 262144
#define IN_F 64
#define HID 128
#define PE_F 16
#define HEADS 4
#define DK 32
#define OUT_F 10

typedef __bf16 bf16x8 __attribute__((ext_vector_type(8)));
typedef float f32x4 __attribute__((ext_vector_type(4)));

struct Sel4 { float* o[4]; const float* b[4]; int slot[4]; };
struct WSrc24 { const float* w[24]; };

// ---------------------------------------------------------------------------
// init: CSR-by-dst build
// ---------------------------------------------------------------------------
__global__ void zero_int_kernel(int* __restrict__ p, int n) {
    int i = blockIdx.x * 256 + threadIdx.x;
    if (i < n) p[i] = 0;
}

__global__ void hist_kernel(const int* __restrict__ dst, int* __restrict__ deg) {
    int e = blockIdx.x * 256 + threadIdx.x;
    if (e < E_E) atomicAdd(&deg[dst[e]], 1);
}

__global__ __launch_bounds__(1024) void scan_kernel(const int* __restrict__ deg,
                                                    int* __restrict__ row_ptr,
                                                    int* __restrict__ cursor) {
    __shared__ int lds[1024];
    int tid = threadIdx.x;
    int base = tid * 16;
    int d[16];
    int s = 0;
#pragma unroll
    for (int i = 0; i < 16; i++) { d[i] = deg[base + i]; s += d[i]; }
    lds[tid] = s;
    __syncthreads();
    for (int off = 1; off < 1024; off <<= 1) {
        int v = (tid >= off) ? lds[tid - off] : 0;
        __syncthreads();
        lds[tid] += v;
        __syncthreads();
    }
    int run = lds[tid] - s;  // exclusive prefix
#pragma unroll
    for (int i = 0; i < 16; i++) {
        row_ptr[base + i] = run;
        cursor[base + i] = run;
        run += d[i];
    }
    if (tid == 1023) row_ptr[N_N] = run;
}

__global__ void scatter_kernel(const int* __restrict__ src, const int* __restrict__ dst,
                               int* __restrict__ cursor, int* __restrict__ perm,
                               int* __restrict__ ssrc, int* __restrict__ sdst) {
    int e = blockIdx.x * 256 + threadIdx.x;
    if (e >= E_E) return;
    int dd = dst[e];
    int pos = atomicAdd(&cursor[dd], 1);
    perm[pos] = e;
    ssrc[pos] = src[e];
    sdst[pos] = dd;
}

// ---------------------------------------------------------------------------
// weight prepack: fp32 W[k][n] (128x128) -> bf16 hi/lo in MFMA B-frag order.
// packed index p: j=p&7, lane=(p>>3)&63, kc=(p>>9)&3, nt=p>>11
//   k = kc*32 + (lane>>4)*8 + j ; n = nt*16 + (lane&15)
// 96 blocks: 4 blocks per matrix.
// ---------------------------------------------------------------------------
__global__ __launch_bounds__(256) void pack_w_kernel(WSrc24 ws, __bf16* __restrict__ Whi,
                                                     __bf16* __restrict__ Wlo) {
    int m = blockIdx.x >> 2, part = blockIdx.x & 3;
    const float* W = ws.w[m];
    int tid = threadIdx.x;
    for (int i = part * 16; i < part * 16 + 16; i++) {
        int p = i * 256 + tid;
        int j = p & 7, lane = (p >> 3) & 63, kc = (p >> 9) & 3, nt = p >> 11;
        int k = kc * 32 + (lane >> 4) * 8 + j;
        int n = nt * 16 + (lane & 15);
        float w = W[k * 128 + n];
        __bf16 h = (__bf16)w;
        Whi[(long)m * 16384 + p] = h;
        Wlo[(long)m * 16384 + p] = (__bf16)(w - (float)h);
    }
}

// ---------------------------------------------------------------------------
// embed: h = [x@node_w+node_b | pe@pe_w+pe_b]
// ---------------------------------------------------------------------------
__global__ void embed_kernel(const float* __restrict__ x, const float* __restrict__ pe,
                             const float* __restrict__ node_w, const float* __restrict__ node_b,
                             const float* __restrict__ pe_w, const float* __restrict__ pe_b,
                             float* __restrict__ h) {
    int idx = blockIdx.x * 256 + threadIdx.x;
    if (idx >= N_N * HID) return;
    int i = idx >> 7, c = idx & 127;
    float acc;
    if (c < 112) {
        acc = node_b[c];
        const float* xr = x + (long)i * IN_F;
        for (int k = 0; k < IN_F; k++) acc += xr[k] * node_w[k * 112 + c];
    } else {
        int cc = c - 112;
        acc = pe_b[cc];
        const float* pr = pe + (long)i * PE_F;
        for (int k = 0; k < PE_F; k++) acc += pr[k] * pe_w[k * PE_F + cc];
    }
    h[idx] = acc;
}

// ---------------------------------------------------------------------------
// MFMA GEMM v3 (R3 base, 2x rows/wave): C[M][128] = A[M][128] @ W + bias.
// Block = 4 waves, 128 rows/block; wave owns 32 rows x 128 cols as two
// stacked 16x128 tiles. All 16 A-float4 loads issued up front; B-frags
// loaded per (nt,kc) from L2 and reused by both row-tiles (6 MFMA : 2 loads).
// No LDS staging / no barrier in the main path.
// blockIdx.y selects matrix/out/bias. MODE 1 (edge): A rows via perm
// (layer 0), epilogue += Dx[sdst]+Ex[ssrc], BN stats reduced
// (shfl -> LDS -> 256 atomics/block) into stats_acc[256].
// ---------------------------------------------------------------------------
template <int MODE>
__global__ __launch_bounds__(256) void mfma_gemm_kernel(
    const float* __restrict__ A, const int* __restrict__ perm,
    const __bf16* __restrict__ Whi, const __bf16* __restrict__ Wlo, Sel4 sel,
    const float* __restrict__ Dx, const float* __restrict__ Ex,
    const int* __restrict__ sdst, const int* __restrict__ ssrc,
    float* __restrict__ stats_acc) {
    __shared__ float sred[1024];  // MODE1 stats reduce (4 waves x 256)
    int tid = threadIdx.x;
    int lane = tid & 63, wave = tid >> 6;
    int l15 = lane & 15, quad = lane >> 4;
    int y = blockIdx.y;
    float* out = sel.o[y];
    const float* bias = sel.b[y];
    const bf16x8* whv = (const bf16x8*)(Whi + (long)sel.slot[y] * 16384);
    const bf16x8* wlv = (const bf16x8*)(Wlo + (long)sel.slot[y] * 16384);

    long r0 = (long)blockIdx.x * 128 + wave * 32;
    long ra0 = r0 + l15, ra1 = r0 + 16 + l15;
    if (MODE == 1 && perm) { ra0 = perm[ra0]; ra1 = perm[ra1]; }

    // issue all 16 A loads, then convert to bf16 hi/lo
    float4 av[2][8];
    {
        const float* Ap0 = A + ra0 * 128 + quad * 8;
        const float* Ap1 = A + ra1 * 128 + quad * 8;
#pragma unroll
        for (int kc = 0; kc < 4; kc++) {
            av[0][kc * 2] = *(const float4*)(Ap0 + kc * 32);
            av[0][kc * 2 + 1] = *(const float4*)(Ap0 + kc * 32 + 4);
            av[1][kc * 2] = *(const float4*)(Ap1 + kc * 32);
            av[1][kc * 2 + 1] = *(const float4*)(Ap1 + kc * 32 + 4);
        }
    }
    bf16x8 ahi[2][4], alo[2][4];
#pragma unroll
    for (int t = 0; t < 2; t++)
#pragma unroll
        for (int kc = 0; kc < 4; kc++) {
            float fv[8] = {av[t][kc * 2].x, av[t][kc * 2].y, av[t][kc * 2].z, av[t][kc * 2].w,
                           av[t][kc * 2 + 1].x, av[t][kc * 2 + 1].y, av[t][kc * 2 + 1].z,
                           av[t][kc * 2 + 1].w};
#pragma unroll
            for (int j = 0; j < 8; j++) {
                __bf16 hh = (__bf16)fv[j];
                ahi[t][kc][j] = hh;
                alo[t][kc][j] = (__bf16)(fv[j] - (float)hh);
            }
        }

    f32x4 acc[2][8];
#pragma unroll
    for (int t = 0; t < 2; t++)
#pragma unroll
        for (int nt = 0; nt < 8; nt++) acc[t][nt] = (f32x4){0.f, 0.f, 0.f, 0.f};

#pragma unroll
    for (int nt = 0; nt < 8; nt++) {
#pragma unroll
        for (int kc = 0; kc < 4; kc++) {
            bf16x8 bhi = whv[(nt * 4 + kc) * 64 + lane];
            bf16x8 blo = wlv[(nt * 4 + kc) * 64 + lane];
            acc[0][nt] = __builtin_amdgcn_mfma_f32_16x16x32_bf16(ahi[0][kc], blo, acc[0][nt], 0, 0, 0);
            acc[1][nt] = __builtin_amdgcn_mfma_f32_16x16x32_bf16(ahi[1][kc], blo, acc[1][nt], 0, 0, 0);
            acc[0][nt] = __builtin_amdgcn_mfma_f32_16x16x32_bf16(alo[0][kc], bhi, acc[0][nt], 0, 0, 0);
            acc[1][nt] = __builtin_amdgcn_mfma_f32_16x16x32_bf16(alo[1][kc], bhi, acc[1][nt], 0, 0, 0);
            acc[0][nt] = __builtin_amdgcn_mfma_f32_16x16x32_bf16(ahi[0][kc], bhi, acc[0][nt], 0, 0, 0);
            acc[1][nt] = __builtin_amdgcn_mfma_f32_16x16x32_bf16(ahi[1][kc], bhi, acc[1][nt], 0, 0, 0);
        }
    }

    // epilogue. C/D layout: col = lane&15, row = quad*4 + reg  [verified m89/m91]
    float csum[8], csq[8];
#pragma unroll
    for (int nt = 0; nt < 8; nt++) { csum[nt] = 0.f; csq[nt] = 0.f; }

#pragma unroll
    for (int t = 0; t < 2; t++) {
        long rb = r0 + t * 16 + quad * 4;
        int sd[4], ss[4];
        if (MODE == 1) {
#pragma unroll
            for (int r = 0; r < 4; r++) { sd[r] = sdst[rb + r]; ss[r] = ssrc[rb + r]; }
        }
#pragma unroll
        for (int nt = 0; nt < 8; nt++) {
            int c = nt * 16 + l15;
            float bb = bias[c];
#pragma unroll
            for (int r = 0; r < 4; r++) {
                float v = acc[t][nt][r] + bb;
                if (MODE == 1) v += Dx[(long)sd[r] * 128 + c] + Ex[(long)ss[r] * 128 + c];
                out[(rb + r) * 128 + c] = v;
                if (MODE == 1) { csum[nt] += v; csq[nt] += v * v; }
            }
        }
    }

    if (MODE == 1) {
#pragma unroll
        for (int nt = 0; nt < 8; nt++) {
            float s = csum[nt];
            s += __shfl_xor(s, 16); s += __shfl_xor(s, 32);
            float q = csq[nt];
            q += __shfl_xor(q, 16); q += __shfl_xor(q, 32);
            if (quad == 0) {
                sred[wave * 256 + nt * 16 + l15] = s;
                sred[wave * 256 + 128 + nt * 16 + l15] = q;
            }
        }
        __syncthreads();
        if (tid < 256) {
            float v = sred[tid] + sred[256 + tid] + sred[512 + tid] + sred[768 + tid];
            atomicAdd(&stats_acc[tid], v);
        }
    }
}

// stats_acc[0..127]=sum, [128..255]=sumsq -> stat[0..127]=mu, [128..255]=rsig
__global__ void ebn_finalize_kernel(const float* __restrict__ acc, float invM,
                                    float* __restrict__ stat) {
    int c = threadIdx.x;  // 128
    float mu = acc[c] * invM;
    float var = acc[128 + c] * invM - mu * mu;
    stat[c] = mu;
    stat[128 + c] = rsqrtf(var + 1e-5f);
}

// ---------------------------------------------------------------------------
// BN batch stats (node path): partial sums/sumsq per channel
// ---------------------------------------------------------------------------
__global__ __launch_bounds__(256) void bn_stats_kernel(const float* __restrict__ v, long M,
                                                       float* __restrict__ partial) {
    __shared__ float lds[256];
    int tid = threadIdx.x;
    int c = tid & 127, half = tid >> 7;
    float sum = 0.f, sq = 0.f;
    for (long r = (long)blockIdx.x * 2 + half; r < M; r += (long)gridDim.x * 2) {
        float x = v[r * 128 + c];
        sum += x; sq += x * x;
    }
    lds[tid] = sum;
    __syncthreads();
    if (half == 0) sum += lds[tid + 128];
    __syncthreads();
    lds[tid] = sq;
    __syncthreads();
    if (half == 0) {
        sq += lds[tid + 128];
        partial[(long)blockIdx.x * 256 + c] = sum;
        partial[(long)blockIdx.x * 256 + 128 + c] = sq;
    }
}

__global__ void bn_finalize_kernel(const float* __restrict__ partial, int nblk, float invM,
                                   float* __restrict__ stat) {
    int c = threadIdx.x;  // 128 threads
    float s = 0.f, q = 0.f;
    for (int i = 0; i < nblk; i++) {
        s += partial[i * 256 + c];
        q += partial[i * 256 + 128 + c];
    }
    float mu = s * invM;
    float var = q * invM - mu * mu;
    stat[c] = mu;
    stat[128 + c] = rsqrtf(var + 1e-5f);
}

// io = relu(g*(vin-mu)*rsig + b) + io   (elementwise, float4)
__global__ void bn_apply_res_kernel(const float* __restrict__ vin, const float* __restrict__ stat,
                                    const float* __restrict__ g, const float* __restrict__ b,
                                    float* __restrict__ io, long M4) {
    long idx = (long)blockIdx.x * 256 + threadIdx.x;
    if (idx >= M4) return;
    int c4 = (idx & 31) << 2;
    float4 x = ((const float4*)vin)[idx];
    float4 res = ((float4*)io)[idx];
    float xv[4] = {x.x, x.y, x.z, x.w};
    float rv[4] = {res.x, res.y, res.z, res.w};
    float o[4];
#pragma unroll
    for (int t = 0; t < 4; t++) {
        int c = c4 + t;
        float y = g[c] * (xv[t] - stat[c]) * stat[128 + c] + b[c];
        o[t] = fmaxf(y, 0.f) + rv[t];
    }
    ((float4*)io)[idx] = make_float4(o[0], o[1], o[2], o[3]);
}

// ---------------------------------------------------------------------------
// fused aggregation + edge BN/relu/residual, v2: one dst per WAVE (4/block),
// float2 per lane, CSR loop unrolled x2 for memory-level parallelism.
// ---------------------------------------------------------------------------
__global__ __launch_bounds__(256) void agg_bn_kernel(
    const float* __restrict__ eij, const float* __restrict__ Bx, const float* __restrict__ Ax,
    const int* __restrict__ row_ptr, const int* __restrict__ ssrc,
    const float* __restrict__ estat, const float* __restrict__ g, const float* __restrict__ b,
    const float* __restrict__ eold, const int* __restrict__ perm,
    float* __restrict__ e_out, float* __restrict__ hnew) {
    int wave = threadIdx.x >> 6, lane = threadIdx.x & 63;
    int i = blockIdx.x * 4 + wave;
    int c = lane << 1;
    int s0 = row_ptr[i], s1 = row_ptr[i + 1];
    float2 mu = *(const float2*)&estat[c];
    float2 rs = *(const float2*)&estat[128 + c];
    float2 gg = *(const float2*)&g[c];
    float2 bb = *(const float2*)&b[c];
    float nx = 0.f, ny = 0.f, dx = 0.f, dy = 0.f;

    int j = s0;
    for (; j + 2 <= s1; j += 2) {
        int src0 = ssrc[j], src1 = ssrc[j + 1];
        long er0 = perm ? (long)perm[j] : (long)j;
        long er1 = perm ? (long)perm[j + 1] : (long)(j + 1);
        float2 x0 = *(const float2*)&eij[(long)j * 128 + c];
        float2 x1 = *(const float2*)&eij[(long)(j + 1) * 128 + c];
        float2 bx0 = *(const float2*)&Bx[(long)src0 * 128 + c];
        float2 bx1 = *(const float2*)&Bx[(long)src1 * 128 + c];
        float2 o0 = *(const float2*)&eold[er0 * 128 + c];
        float2 o1 = *(const float2*)&eold[er1 * 128 + c];
        float s0x = 1.f / (1.f + __expf(-x0.x)), s0y = 1.f / (1.f + __expf(-x0.y));
        float s1x = 1.f / (1.f + __expf(-x1.x)), s1y = 1.f / (1.f + __expf(-x1.y));
        nx += s0x * bx0.x + s1x * bx1.x;
        ny += s0y * bx0.y + s1y * bx1.y;
        dx += s0x + s1x;
        dy += s0y + s1y;
        float2 y0, y1;
        y0.x = fmaxf(gg.x * (x0.x - mu.x) * rs.x + bb.x, 0.f) + o0.x;
        y0.y = fmaxf(gg.y * (x0.y - mu.y) * rs.y + bb.y, 0.f) + o0.y;
        y1.x = fmaxf(gg.x * (x1.x - mu.x) * rs.x + bb.x, 0.f) + o1.x;
        y1.y = fmaxf(gg.y * (x1.y - mu.y) * rs.y + bb.y, 0.f) + o1.y;
        *(float2*)&e_out[(long)j * 128 + c] = y0;
        *(float2*)&e_out[(long)(j + 1) * 128 + c] = y1;
    }
    if (j < s1) {
        int src0 = ssrc[j];
        long er0 = perm ? (long)perm[j] : (long)j;
        float2 x0 = *(const float2*)&eij[(long)j * 128 + c];
        float2 bx0 = *(const float2*)&Bx[(long)src0 * 128 + c];
        float2 o0 = *(const float2*)&eold[er0 * 128 + c];
        float s0x = 1.f / (1.f + __expf(-x0.x)), s0y = 1.f / (1.f + __expf(-x0.y));
        nx += s0x * bx0.x; ny += s0y * bx0.y;
        dx += s0x; dy += s0y;
        float2 y0;
        y0.x = fmaxf(gg.x * (x0.x - mu.x) * rs.x + bb.x, 0.f) + o0.x;
        y0.y = fmaxf(gg.y * (x0.y - mu.y) * rs.y + bb.y, 0.f) + o0.y;
        *(float2*)&e_out[(long)j * 128 + c] = y0;
    }

    long idx = (long)i * 128 + c;
    float2 ax = *(const float2*)&Ax[idx];
    float2 hv;
    hv.x = ax.x + nx / (dx + 1e-6f);
    hv.y = ax.y + ny / (dy + 1e-6f);
    *(float2*)&hnew[idx] = hv;
}

// ---------------------------------------------------------------------------
// fused attention per (batch, head): scores+sph-softmax+PV, K/V in LDS
// ---------------------------------------------------------------------------
__global__ __launch_bounds__(256) void attn_kernel(const float* __restrict__ q,
                                                   const float* __restrict__ k,
                                                   const float* __restrict__ v,
                                                   const float* __restrict__ sph,
                                                   float* __restrict__ o) {
    __shared__ float k_lds[128 * 32];
    __shared__ float v_lds[128 * 32];
    int b = blockIdx.x >> 2, hd = blockIdx.x & 3;
    int tid = threadIdx.x;

    for (int i = tid; i < 1024; i += 256) {
        int t = i >> 3, d4 = i & 7;
        long gidx = (long)(b * 128 + t) * 32 + hd * 8 + d4;
        ((float4*)k_lds)[t * 8 + d4] = ((const float4*)k)[gidx];
        ((float4*)v_lds)[t * 8 + d4] = ((const float4*)v)[gidx];
    }
    __syncthreads();

    int s = tid >> 1, t0 = (tid & 1) * 64;
    float4 qreg[8];
    long qbase = (long)(b * 128 + s) * 32 + hd * 8;
#pragma unroll
    for (int j = 0; j < 8; j++) qreg[j] = ((const float4*)q)[qbase + j];
    const float* sphrow = sph + ((long)b * 128 + s) * 128 + t0;
    const float inv_sqrt_dk = 0.17677669529663687f;

    float p[64];
#pragma unroll
    for (int i = 0; i < 64; i++) {
        const float4* kr = (const float4*)&k_lds[(t0 + i) * 32];
        float acc = 0.f;
#pragma unroll
        for (int j = 0; j < 8; j++) {
            float4 kv = kr[j];
            acc += qreg[j].x * kv.x + qreg[j].y * kv.y + qreg[j].z * kv.z + qreg[j].w * kv.w;
        }
        p[i] = acc * inv_sqrt_dk * sphrow[i];
    }
    float m = -1e30f;
#pragma unroll
    for (int i = 0; i < 64; i++) m = fmaxf(m, p[i]);
    m = fmaxf(m, __shfl_xor(m, 1));
    float l = 0.f;
#pragma unroll
    for (int i = 0; i < 64; i++) {
        p[i] = __expf(p[i] - m);
        l += p[i];
    }
    l += __shfl_xor(l, 1);
    float invl = 1.f / l;

    float part[32];
#pragma unroll
    for (int d = 0; d < 32; d++) part[d] = 0.f;
#pragma unroll
    for (int i = 0; i < 64; i++) {
        float pv = p[i] * invl;
        const float4* vr = (const float4*)&v_lds[(t0 + i) * 32];
#pragma unroll
        for (int j = 0; j < 8; j++) {
            float4 vv = vr[j];
            part[4 * j + 0] += pv * vv.x;
            part[4 * j + 1] += pv * vv.y;
            part[4 * j + 2] += pv * vv.z;
            part[4 * j + 3] += pv * vv.w;
        }
    }
    int halfw = tid & 1;
    float outv[16];
#pragma unroll
    for (int d = 0; d < 32; d++) {
        float tot = part[d] + __shfl_xor(part[d], 1);
        if ((d >> 4) == halfw) outv[d & 15] = tot;
    }
    long obase = (long)(b * 128 + s) * 32 + hd * 8 + halfw * 4;
#pragma unroll
    for (int j = 0; j < 4; j++)
        ((float4*)o)[obase + j] = make_float4(outv[4 * j], outv[4 * j + 1], outv[4 * j + 2], outv[4 * j + 3]);
}

// ---------------------------------------------------------------------------
// mean-pool per graph + 3-layer MLP
// ---------------------------------------------------------------------------
__global__ __launch_bounds__(128) void pool_mlp_kernel(
    const float* __restrict__ h, const float* __restrict__ w1, const float* __restrict__ b1,
    const float* __restrict__ w2, const float* __restrict__ b2, const float* __restrict__ w3,
    const float* __restrict__ b3, float* __restrict__ out) {
    __shared__ float g[128], m1[64], m2[32];
    int b = blockIdx.x, tid = threadIdx.x;
    const float* hb = h + (long)b * 128 * 128;
    float s = 0.f;
    for (int r = 0; r < 128; r++) s += hb[r * 128 + tid];
    g[tid] = s * (1.f / 128.f);
    __syncthreads();
    if (tid < 64) {
        float a = b1[tid];
        for (int kk = 0; kk < 128; kk++) a += g[kk] * w1[kk * 64 + tid];
        m1[tid] = fmaxf(a, 0.f);
    }
    __syncthreads();
    if (tid < 32) {
        float a = b2[tid];
        for (int kk = 0; kk < 64; kk++) a += m1[kk] * w2[kk * 32 + tid];
        m2[tid] = fmaxf(a, 0.f);
    }
    __syncthreads();
    if (tid < 10) {
        float a = b3[tid];
        for (int kk = 0; kk < 32; kk++) a += m2[kk] * w3[kk * 10 + tid];
        out[b * 10 + tid] = a;
    }
}

// ---------------------------------------------------------------------------
extern "C" void kernel_launch(void* const* d_in, const int* in_sizes, int n_in,
                              void* d_out, int out_size, void* d_ws, size_t ws_size,
                              hipStream_t stream) {
    (void)in_sizes; (void)n_in; (void)out_size;
    const float* x        = (const float*)d_in[0];
    const float* pe       = (const float*)d_in[1];
    const float* edge_attr= (const float*)d_in[2];
    const float* sph      = (const float*)d_in[3];
    const float* node_w   = (const float*)d_in[4];
    const float* node_b   = (const float*)d_in[5];
    const float* pe_w     = (const float*)d_in[6];
    const float* pe_b     = (const float*)d_in[7];
    const float* conv_Aw  = (const float*)d_in[8];
    const float* conv_Ab  = (const float*)d_in[9];
    const float* conv_Bw  = (const float*)d_in[10];
    const float* conv_Bb  = (const float*)d_in[11];
    const float* conv_Cw  = (const float*)d_in[12];
    const float* conv_Cb  = (const float*)d_in[13];
    const float* conv_Dw  = (const float*)d_in[14];
    const float* conv_Db  = (const float*)d_in[15];
    const float* conv_Ew  = (const float*)d_in[16];
    const float* conv_Eb  = (const float*)d_in[17];
    const float* bnx_g    = (const float*)d_in[18];
    const float* bnx_b    = (const float*)d_in[19];
    const float* bne_g    = (const float*)d_in[20];
    const float* bne_b    = (const float*)d_in[21];
    const float* attn_w   = (const float*)d_in[22];
    const float* attn_b   = (const float*)d_in[23];
    const float* mlp1_w   = (const float*)d_in[24];
    const float* mlp1_b   = (const float*)d_in[25];
    const float* mlp2_w   = (const float*)d_in[26];
    const float* mlp2_b   = (const float*)d_in[27];
    const float* mlp3_w   = (const float*)d_in[28];
    const float* mlp3_b   = (const float*)d_in[29];
    const int*   eidx     = (const int*)d_in[30];
    const int* esrc = eidx;
    const int* edst = eidx + E_E;
    float* out = (float*)d_out;

    // workspace carve (floats first, then bf16 packs, then ints)
    float* f = (float*)d_ws;
    float* h      = f; f += (long)N_N * HID;
    float* hnew   = f; f += (long)N_N * HID;
    float* Ax     = f; f += (long)N_N * HID;   // q later
    float* Bx     = f; f += (long)N_N * HID;   // k later
    float* Dx     = f; f += (long)N_N * HID;   // v later
    float* Ex     = f; f += (long)N_N * HID;   // o later
    float* e      = f; f += (long)E_E * HID;
    float* eij    = f; f += (long)E_E * HID;
    float* partial= f; f += 512 * 256;
    float* bnxs   = f; f += 256;
    float* bnes   = f; f += 256;
    float* ebn_acc= f; f += 256;
    __bf16* Whi = (__bf16*)f;           // 24 * 16384 bf16
    __bf16* Wlo = Whi + 24 * 16384;
    int* ip = (int*)(Wlo + 24 * 16384);
    int* deg     = ip; ip += N_N;
    int* row_ptr = ip; ip += N_N + 1;
    int* cursor  = ip; ip += N_N;
    int* perm    = ip; ip += E_E;
    int* ssrc    = ip; ip += E_E;
    int* sdst    = ip; ip += E_E;
    size_t need = (size_t)((char*)ip - (char*)d_ws);
    if (ws_size < need) return;  // out stays poisoned: signals ws too small

    // ---- pack all weight matrices (bf16 hi/lo, MFMA B-frag order) ----
    WSrc24 wsrc;
    for (int l = 0; l < L_LAYERS; l++) {
        wsrc.w[l * 5 + 0] = conv_Aw + l * 16384;
        wsrc.w[l * 5 + 1] = conv_Bw + l * 16384;
        wsrc.w[l * 5 + 2] = conv_Cw + l * 16384;
        wsrc.w[l * 5 + 3] = conv_Dw + l * 16384;
        wsrc.w[l * 5 + 4] = conv_Ew + l * 16384;
    }
    for (int m = 0; m < 4; m++) wsrc.w[20 + m] = attn_w + m * 16384;
    pack_w_kernel<<<96, 256, 0, stream>>>(wsrc, Whi, Wlo);

    // ---- build CSR by dst ----
    zero_int_kernel<<<(N_N + 255) / 256, 256, 0, stream>>>(deg, N_N);
    hist_kernel<<<E_E / 256, 256, 0, stream>>>(edst, deg);
    scan_kernel<<<1, 1024, 0, stream>>>(deg, row_ptr, cursor);
    scatter_kernel<<<E_E / 256, 256, 0, stream>>>(esrc, edst, cursor, perm, ssrc, sdst);

    embed_kernel<<<N_N * HID / 256, 256, 0, stream>>>(x, pe, node_w, node_b, pe_w, pe_b, h);

    for (int l = 0; l < L_LAYERS; l++) {
        zero_int_kernel<<<1, 256, 0, stream>>>((int*)ebn_acc, 256);

        // ABDE node GEMMs batched: y selects matrix. 128 rows/block.
        Sel4 selN;
        selN.o[0] = Ax; selN.b[0] = conv_Ab + l * 128; selN.slot[0] = l * 5 + 0;
        selN.o[1] = Bx; selN.b[1] = conv_Bb + l * 128; selN.slot[1] = l * 5 + 1;
        selN.o[2] = Dx; selN.b[2] = conv_Db + l * 128; selN.slot[2] = l * 5 + 3;
        selN.o[3] = Ex; selN.b[3] = conv_Eb + l * 128; selN.slot[3] = l * 5 + 4;
        mfma_gemm_kernel<0><<<dim3(N_N / 128, 4), 256, 0, stream>>>(
            h, nullptr, Whi, Wlo, selN, nullptr, nullptr, nullptr, nullptr, nullptr);

        // edge GEMM: eij = e@Cw + Cb + Dx[dst] + Ex[src], fused BN stats
        const float* Asrc = (l == 0) ? edge_attr : e;
        const int* permA = (l == 0) ? perm : nullptr;
        Sel4 selE;
        selE.o[0] = eij; selE.b[0] = conv_Cb + l * 128; selE.slot[0] = l * 5 + 2;
        selE.o[1] = selE.o[2] = selE.o[3] = eij;
        selE.b[1] = selE.b[2] = selE.b[3] = selE.b[0];
        selE.slot[1] = selE.slot[2] = selE.slot[3] = selE.slot[0];
        mfma_gemm_kernel<1><<<dim3(E_E / 128, 1), 256, 0, stream>>>(
            Asrc, permA, Whi, Wlo, selE, Dx, Ex, sdst, ssrc, ebn_acc);

        ebn_finalize_kernel<<<1, 128, 0, stream>>>(ebn_acc, 1.f / E_E, bnes);

        // fused: aggregation (hnew) + edge BN/relu/residual (e update)
        const float* eoldSrc = (l == 0) ? edge_attr : e;
        const int* permE = (l == 0) ? perm : nullptr;
        agg_bn_kernel<<<N_N / 4, 256, 0, stream>>>(eij, Bx, Ax, row_ptr, ssrc, bnes,
                                                   bne_g + l * 128, bne_b + l * 128,
                                                   eoldSrc, permE, e, hnew);

        bn_stats_kernel<<<128, 256, 0, stream>>>(hnew, (long)N_N, partial);
        bn_finalize_kernel<<<1, 128, 0, stream>>>(partial, 128, 1.f / N_N, bnxs);
        bn_apply_res_kernel<<<N_N * 32 / 256, 256, 0, stream>>>(
            hnew, bnxs, bnx_g + l * 128, bnx_b + l * 128, h, (long)N_N * 32);

        // qkv batched: q=Ax, k=Bx, v=Dx
        Sel4 selQ;
        selQ.o[0] = Ax; selQ.b[0] = attn_b;       selQ.slot[0] = 20;
        selQ.o[1] = Bx; selQ.b[1] = attn_b + 128; selQ.slot[1] = 21;
        selQ.o[2] = Dx; selQ.b[2] = attn_b + 256; selQ.slot[2] = 22;
        selQ.o[3] = Dx; selQ.b[3] = attn_b + 256; selQ.slot[3] = 22;
        mfma_gemm_kernel<0><<<dim3(N_N / 128, 3), 256, 0, stream>>>(
            h, nullptr, Whi, Wlo, selQ, nullptr, nullptr, nullptr, nullptr, nullptr);

        attn_kernel<<<B_G * HEADS, 256, 0, stream>>>(Ax, Bx, Dx, sph, Ex);

        // output projection: h = o @ Wproj + b
        Sel4 selP;
        selP.o[0] = h; selP.b[0] = attn_b + 384; selP.slot[0] = 23;
        selP.o[1] = selP.o[2] = selP.o[3] = h;
        selP.b[1] = selP.b[2] = selP.b[3] = selP.b[0];
        selP.slot[1] = selP.slot[2] = selP.slot[3] = selP.slot[0];
        mfma_gemm_kernel<0><<<dim3(N_N / 128, 1), 256, 0, stream>>>(
            Ex, nullptr, Whi, Wlo, selP, nullptr, nullptr, nullptr, nullptr, nullptr);
    }

    pool_mlp_kernel<<<B_G, 128, 0, stream>>>(h, mlp1_w, mlp1_b, mlp2_w, mlp2_b, mlp3_w, mlp3_b, out);
}

// Round 7
// 1784.970 us; speedup vs baseline: 1.1483x; 1.1483x over previous
//
#include <hip/hip_runtime.h>
#include <math.h>

// Problem constants
#define L_LAYERS 4
#define B_G 128
#define S_G 128
#define N_N 16384      // B*S
#define E_E 262144
#define IN_F 64
#define HID 128
#define PE_F 16
#define HEADS 4
#define DK 32
#define OUT_F 10

typedef __bf16 bf16x8 __attribute__((ext_vector_type(8)));
typedef float f32x4 __attribute__((ext_vector_type(4)));

struct Sel4 { float* o[4]; const float* b[4]; int slot[4]; };
struct WSrc24 { const float* w[24]; };

#define STATS_REP 32   // stats atomic replicas (contention: 4096 blocks -> 128/addr)

// ---------------------------------------------------------------------------
// init: CSR-by-dst build
// ---------------------------------------------------------------------------
__global__ void zero_int_kernel(int* __restrict__ p, int n) {
    int i = blockIdx.x * 256 + threadIdx.x;
    if (i < n) p[i] = 0;
}

__global__ void hist_kernel(const int* __restrict__ dst, int* __restrict__ deg) {
    int e = blockIdx.x * 256 + threadIdx.x;
    if (e < E_E) atomicAdd(&deg[dst[e]], 1);
}

__global__ __launch_bounds__(1024) void scan_kernel(const int* __restrict__ deg,
                                                    int* __restrict__ row_ptr,
                                                    int* __restrict__ cursor) {
    __shared__ int lds[1024];
    int tid = threadIdx.x;
    int base = tid * 16;
    int d[16];
    int s = 0;
#pragma unroll
    for (int i = 0; i < 16; i++) { d[i] = deg[base + i]; s += d[i]; }
    lds[tid] = s;
    __syncthreads();
    for (int off = 1; off < 1024; off <<= 1) {
        int v = (tid >= off) ? lds[tid - off] : 0;
        __syncthreads();
        lds[tid] += v;
        __syncthreads();
    }
    int run = lds[tid] - s;  // exclusive prefix
#pragma unroll
    for (int i = 0; i < 16; i++) {
        row_ptr[base + i] = run;
        cursor[base + i] = run;
        run += d[i];
    }
    if (tid == 1023) row_ptr[N_N] = run;
}

__global__ void scatter_kernel(const int* __restrict__ src, const int* __restrict__ dst,
                               int* __restrict__ cursor, int* __restrict__ perm,
                               int* __restrict__ ssrc, int* __restrict__ sdst) {
    int e = blockIdx.x * 256 + threadIdx.x;
    if (e >= E_E) return;
    int dd = dst[e];
    int pos = atomicAdd(&cursor[dd], 1);
    perm[pos] = e;
    ssrc[pos] = src[e];
    sdst[pos] = dd;
}

// ---------------------------------------------------------------------------
// weight prepack: fp32 W[k][n] (128x128) -> bf16 hi/lo in MFMA B-frag order.
// packed index p: j=p&7, lane=(p>>3)&63, kc=(p>>9)&3, nt=p>>11
//   k = kc*32 + (lane>>4)*8 + j ; n = nt*16 + (lane&15)
// 96 blocks: 4 blocks per matrix.
// ---------------------------------------------------------------------------
__global__ __launch_bounds__(256) void pack_w_kernel(WSrc24 ws, __bf16* __restrict__ Whi,
                                                     __bf16* __restrict__ Wlo) {
    int m = blockIdx.x >> 2, part = blockIdx.x & 3;
    const float* W = ws.w[m];
    int tid = threadIdx.x;
    for (int i = part * 16; i < part * 16 + 16; i++) {
        int p = i * 256 + tid;
        int j = p & 7, lane = (p >> 3) & 63, kc = (p >> 9) & 3, nt = p >> 11;
        int k = kc * 32 + (lane >> 4) * 8 + j;
        int n = nt * 16 + (lane & 15);
        float w = W[k * 128 + n];
        __bf16 h = (__bf16)w;
        Whi[(long)m * 16384 + p] = h;
        Wlo[(long)m * 16384 + p] = (__bf16)(w - (float)h);
    }
}

// ---------------------------------------------------------------------------
// embed: h = [x@node_w+node_b | pe@pe_w+pe_b]
// ---------------------------------------------------------------------------
__global__ void embed_kernel(const float* __restrict__ x, const float* __restrict__ pe,
                             const float* __restrict__ node_w, const float* __restrict__ node_b,
                             const float* __restrict__ pe_w, const float* __restrict__ pe_b,
                             float* __restrict__ h) {
    int idx = blockIdx.x * 256 + threadIdx.x;
    if (idx >= N_N * HID) return;
    int i = idx >> 7, c = idx & 127;
    float acc;
    if (c < 112) {
        acc = node_b[c];
        const float* xr = x + (long)i * IN_F;
        for (int k = 0; k < IN_F; k++) acc += xr[k] * node_w[k * 112 + c];
    } else {
        int cc = c - 112;
        acc = pe_b[cc];
        const float* pr = pe + (long)i * PE_F;
        for (int k = 0; k < PE_F; k++) acc += pr[k] * pe_w[k * PE_F + cc];
    }
    h[idx] = acc;
}

// ---------------------------------------------------------------------------
// MFMA GEMM (R3 structure): C[M][128] = A[M][128] @ W + bias, bf16x3 split.
// Block = 4 waves, 64 rows/block; wave owns 16 rows x 128 cols (8 nt-tiles,
// K in 4 chunks of 32). A global->reg (+cvt), B-frags from packed global (L2).
// blockIdx.y selects matrix/out/bias. MODE 1 (edge): A rows via perm
// (layer 0), epilogue += Dx[sdst]+Ex[ssrc], BN stats reduced
// (shfl -> LDS) then 256 atomics/block into replica blockIdx.x & 31.
// ---------------------------------------------------------------------------
template <int MODE>
__global__ __launch_bounds__(256) void mfma_gemm_kernel(
    const float* __restrict__ A, const int* __restrict__ perm,
    const __bf16* __restrict__ Whi, const __bf16* __restrict__ Wlo, Sel4 sel,
    const float* __restrict__ Dx, const float* __restrict__ Ex,
    const int* __restrict__ sdst, const int* __restrict__ ssrc,
    float* __restrict__ stats_acc) {
    __shared__ float sred[1024];  // MODE1 stats reduce (4 waves x 256)
    int tid = threadIdx.x;
    int lane = tid & 63, wave = tid >> 6;
    int l15 = lane & 15, quad = lane >> 4;
    long rowBase = (long)blockIdx.x * 64 + wave * 16;
    int y = blockIdx.y;
    float* out = sel.o[y];
    const float* bias = sel.b[y];
    const bf16x8* whv = (const bf16x8*)(Whi + (long)sel.slot[y] * 16384);
    const bf16x8* wlv = (const bf16x8*)(Wlo + (long)sel.slot[y] * 16384);

    long arow = rowBase + l15;
    if (MODE == 1 && perm) arow = perm[arow];
    const float* Ap = A + arow * 128 + quad * 8;

    f32x4 acc[8];
#pragma unroll
    for (int t = 0; t < 8; t++) acc[t] = (f32x4){0.f, 0.f, 0.f, 0.f};

#pragma unroll
    for (int kc = 0; kc < 4; kc++) {
        float4 a0 = *(const float4*)(Ap + kc * 32);
        float4 a1 = *(const float4*)(Ap + kc * 32 + 4);
        float f[8] = {a0.x, a0.y, a0.z, a0.w, a1.x, a1.y, a1.z, a1.w};
        bf16x8 ahi, alo;
#pragma unroll
        for (int j = 0; j < 8; j++) {
            __bf16 hh = (__bf16)f[j];
            ahi[j] = hh;
            alo[j] = (__bf16)(f[j] - (float)hh);
        }
#pragma unroll
        for (int nt = 0; nt < 8; nt++) {
            bf16x8 bhi = whv[(nt * 4 + kc) * 64 + lane];
            bf16x8 blo = wlv[(nt * 4 + kc) * 64 + lane];
            acc[nt] = __builtin_amdgcn_mfma_f32_16x16x32_bf16(ahi, blo, acc[nt], 0, 0, 0);
            acc[nt] = __builtin_amdgcn_mfma_f32_16x16x32_bf16(alo, bhi, acc[nt], 0, 0, 0);
            acc[nt] = __builtin_amdgcn_mfma_f32_16x16x32_bf16(ahi, bhi, acc[nt], 0, 0, 0);
        }
    }

    // epilogue. C/D layout: col = lane&15, row = quad*4 + reg  [verified m89/m91]
    int sd[4], ss[4];
    if (MODE == 1) {
#pragma unroll
        for (int r = 0; r < 4; r++) {
            long row = rowBase + quad * 4 + r;
            sd[r] = sdst[row];
            ss[r] = ssrc[row];
        }
    }
    float csum[8], csq[8];
#pragma unroll
    for (int nt = 0; nt < 8; nt++) { csum[nt] = 0.f; csq[nt] = 0.f; }

#pragma unroll
    for (int nt = 0; nt < 8; nt++) {
        int c = nt * 16 + l15;
        float bb = bias[c];
#pragma unroll
        for (int r = 0; r < 4; r++) {
            long row = rowBase + quad * 4 + r;
            float v = acc[nt][r] + bb;
            if (MODE == 1) v += Dx[(long)sd[r] * 128 + c] + Ex[(long)ss[r] * 128 + c];
            out[row * 128 + c] = v;
            if (MODE == 1) { csum[nt] += v; csq[nt] += v * v; }
        }
    }

    if (MODE == 1) {
#pragma unroll
        for (int nt = 0; nt < 8; nt++) {
            float s = csum[nt];
            s += __shfl_xor(s, 16); s += __shfl_xor(s, 32);
            float q = csq[nt];
            q += __shfl_xor(q, 16); q += __shfl_xor(q, 32);
            if (quad == 0) {
                sred[wave * 256 + nt * 16 + l15] = s;
                sred[wave * 256 + 128 + nt * 16 + l15] = q;
            }
        }
        __syncthreads();
        if (tid < 256) {
            float v = sred[tid] + sred[256 + tid] + sred[512 + tid] + sred[768 + tid];
            // replica to cut same-address atomic contention 4096 -> 128
            atomicAdd(&stats_acc[(blockIdx.x & (STATS_REP - 1)) * 256 + tid], v);
        }
    }
}

// acc[rep][0..127]=sum, [rep][128..255]=sumsq over STATS_REP replicas
__global__ void ebn_finalize_kernel(const float* __restrict__ acc, float invM,
                                    float* __restrict__ stat) {
    int c = threadIdx.x;  // 128
    float s = 0.f, q = 0.f;
    for (int r = 0; r < STATS_REP; r++) {
        s += acc[r * 256 + c];
        q += acc[r * 256 + 128 + c];
    }
    float mu = s * invM;
    float var = q * invM - mu * mu;
    stat[c] = mu;
    stat[128 + c] = rsqrtf(var + 1e-5f);
}

// ---------------------------------------------------------------------------
// BN batch stats (node path): partial sums/sumsq per channel
// ---------------------------------------------------------------------------
__global__ __launch_bounds__(256) void bn_stats_kernel(const float* __restrict__ v, long M,
                                                       float* __restrict__ partial) {
    __shared__ float lds[256];
    int tid = threadIdx.x;
    int c = tid & 127, half = tid >> 7;
    float sum = 0.f, sq = 0.f;
    for (long r = (long)blockIdx.x * 2 + half; r < M; r += (long)gridDim.x * 2) {
        float x = v[r * 128 + c];
        sum += x; sq += x * x;
    }
    lds[tid] = sum;
    __syncthreads();
    if (half == 0) sum += lds[tid + 128];
    __syncthreads();
    lds[tid] = sq;
    __syncthreads();
    if (half == 0) {
        sq += lds[tid + 128];
        partial[(long)blockIdx.x * 256 + c] = sum;
        partial[(long)blockIdx.x * 256 + 128 + c] = sq;
    }
}

__global__ void bn_finalize_kernel(const float* __restrict__ partial, int nblk, float invM,
                                   float* __restrict__ stat) {
    int c = threadIdx.x;  // 128 threads
    float s = 0.f, q = 0.f;
    for (int i = 0; i < nblk; i++) {
        s += partial[i * 256 + c];
        q += partial[i * 256 + 128 + c];
    }
    float mu = s * invM;
    float var = q * invM - mu * mu;
    stat[c] = mu;
    stat[128 + c] = rsqrtf(var + 1e-5f);
}

// io = relu(g*(vin-mu)*rsig + b) + io   (elementwise, float4)
__global__ void bn_apply_res_kernel(const float* __restrict__ vin, const float* __restrict__ stat,
                                    const float* __restrict__ g, const float* __restrict__ b,
                                    float* __restrict__ io, long M4) {
    long idx = (long)blockIdx.x * 256 + threadIdx.x;
    if (idx >= M4) return;
    int c4 = (idx & 31) << 2;
    float4 x = ((const float4*)vin)[idx];
    float4 res = ((float4*)io)[idx];
    float xv[4] = {x.x, x.y, x.z, x.w};
    float rv[4] = {res.x, res.y, res.z, res.w};
    float o[4];
#pragma unroll
    for (int t = 0; t < 4; t++) {
        int c = c4 + t;
        float y = g[c] * (xv[t] - stat[c]) * stat[128 + c] + b[c];
        o[t] = fmaxf(y, 0.f) + rv[t];
    }
    ((float4*)io)[idx] = make_float4(o[0], o[1], o[2], o[3]);
}

// ---------------------------------------------------------------------------
// fused aggregation + edge BN/relu/residual, v2: one dst per WAVE (4/block),
// float2 per lane, CSR loop unrolled x2 for memory-level parallelism.
// ---------------------------------------------------------------------------
__global__ __launch_bounds__(256) void agg_bn_kernel(
    const float* __restrict__ eij, const float* __restrict__ Bx, const float* __restrict__ Ax,
    const int* __restrict__ row_ptr, const int* __restrict__ ssrc,
    const float* __restrict__ estat, const float* __restrict__ g, const float* __restrict__ b,
    const float* __restrict__ eold, const int* __restrict__ perm,
    float* __restrict__ e_out, float* __restrict__ hnew) {
    int wave = threadIdx.x >> 6, lane = threadIdx.x & 63;
    int i = blockIdx.x * 4 + wave;
    int c = lane << 1;
    int s0 = row_ptr[i], s1 = row_ptr[i + 1];
    float2 mu = *(const float2*)&estat[c];
    float2 rs = *(const float2*)&estat[128 + c];
    float2 gg = *(const float2*)&g[c];
    float2 bb = *(const float2*)&b[c];
    float nx = 0.f, ny = 0.f, dx = 0.f, dy = 0.f;

    int j = s0;
    for (; j + 2 <= s1; j += 2) {
        int src0 = ssrc[j], src1 = ssrc[j + 1];
        long er0 = perm ? (long)perm[j] : (long)j;
        long er1 = perm ? (long)perm[j + 1] : (long)(j + 1);
        float2 x0 = *(const float2*)&eij[(long)j * 128 + c];
        float2 x1 = *(const float2*)&eij[(long)(j + 1) * 128 + c];
        float2 bx0 = *(const float2*)&Bx[(long)src0 * 128 + c];
        float2 bx1 = *(const float2*)&Bx[(long)src1 * 128 + c];
        float2 o0 = *(const float2*)&eold[er0 * 128 + c];
        float2 o1 = *(const float2*)&eold[er1 * 128 + c];
        float s0x = 1.f / (1.f + __expf(-x0.x)), s0y = 1.f / (1.f + __expf(-x0.y));
        float s1x = 1.f / (1.f + __expf(-x1.x)), s1y = 1.f / (1.f + __expf(-x1.y));
        nx += s0x * bx0.x + s1x * bx1.x;
        ny += s0y * bx0.y + s1y * bx1.y;
        dx += s0x + s1x;
        dy += s0y + s1y;
        float2 y0, y1;
        y0.x = fmaxf(gg.x * (x0.x - mu.x) * rs.x + bb.x, 0.f) + o0.x;
        y0.y = fmaxf(gg.y * (x0.y - mu.y) * rs.y + bb.y, 0.f) + o0.y;
        y1.x = fmaxf(gg.x * (x1.x - mu.x) * rs.x + bb.x, 0.f) + o1.x;
        y1.y = fmaxf(gg.y * (x1.y - mu.y) * rs.y + bb.y, 0.f) + o1.y;
        *(float2*)&e_out[(long)j * 128 + c] = y0;
        *(float2*)&e_out[(long)(j + 1) * 128 + c] = y1;
    }
    if (j < s1) {
        int src0 = ssrc[j];
        long er0 = perm ? (long)perm[j] : (long)j;
        float2 x0 = *(const float2*)&eij[(long)j * 128 + c];
        float2 bx0 = *(const float2*)&Bx[(long)src0 * 128 + c];
        float2 o0 = *(const float2*)&eold[er0 * 128 + c];
        float s0x = 1.f / (1.f + __expf(-x0.x)), s0y = 1.f / (1.f + __expf(-x0.y));
        nx += s0x * bx0.x; ny += s0y * bx0.y;
        dx += s0x; dy += s0y;
        float2 y0;
        y0.x = fmaxf(gg.x * (x0.x - mu.x) * rs.x + bb.x, 0.f) + o0.x;
        y0.y = fmaxf(gg.y * (x0.y - mu.y) * rs.y + bb.y, 0.f) + o0.y;
        *(float2*)&e_out[(long)j * 128 + c] = y0;
    }

    long idx = (long)i * 128 + c;
    float2 ax = *(const float2*)&Ax[idx];
    float2 hv;
    hv.x = ax.x + nx / (dx + 1e-6f);
    hv.y = ax.y + ny / (dy + 1e-6f);
    *(float2*)&hnew[idx] = hv;
}

// ---------------------------------------------------------------------------
// fused attention per (batch, head): scores+sph-softmax+PV, K/V in LDS
// ---------------------------------------------------------------------------
__global__ __launch_bounds__(256) void attn_kernel(const float* __restrict__ q,
                                                   const float* __restrict__ k,
                                                   const float* __restrict__ v,
                                                   const float* __restrict__ sph,
                                                   float* __restrict__ o) {
    __shared__ float k_lds[128 * 32];
    __shared__ float v_lds[128 * 32];
    int b = blockIdx.x >> 2, hd = blockIdx.x & 3;
    int tid = threadIdx.x;

    for (int i = tid; i < 1024; i += 256) {
        int t = i >> 3, d4 = i & 7;
        long gidx = (long)(b * 128 + t) * 32 + hd * 8 + d4;
        ((float4*)k_lds)[t * 8 + d4] = ((const float4*)k)[gidx];
        ((float4*)v_lds)[t * 8 + d4] = ((const float4*)v)[gidx];
    }
    __syncthreads();

    int s = tid >> 1, t0 = (tid & 1) * 64;
    float4 qreg[8];
    long qbase = (long)(b * 128 + s) * 32 + hd * 8;
#pragma unroll
    for (int j = 0; j < 8; j++) qreg[j] = ((const float4*)q)[qbase + j];
    const float* sphrow = sph + ((long)b * 128 + s) * 128 + t0;
    const float inv_sqrt_dk = 0.17677669529663687f;

    float p[64];
#pragma unroll
    for (int i = 0; i < 64; i++) {
        const float4* kr = (const float4*)&k_lds[(t0 + i) * 32];
        float acc = 0.f;
#pragma unroll
        for (int j = 0; j < 8; j++) {
            float4 kv = kr[j];
            acc += qreg[j].x * kv.x + qreg[j].y * kv.y + qreg[j].z * kv.z + qreg[j].w * kv.w;
        }
        p[i] = acc * inv_sqrt_dk * sphrow[i];
    }
    float m = -1e30f;
#pragma unroll
    for (int i = 0; i < 64; i++) m = fmaxf(m, p[i]);
    m = fmaxf(m, __shfl_xor(m, 1));
    float l = 0.f;
#pragma unroll
    for (int i = 0; i < 64; i++) {
        p[i] = __expf(p[i] - m);
        l += p[i];
    }
    l += __shfl_xor(l, 1);
    float invl = 1.f / l;

    float part[32];
#pragma unroll
    for (int d = 0; d < 32; d++) part[d] = 0.f;
#pragma unroll
    for (int i = 0; i < 64; i++) {
        float pv = p[i] * invl;
        const float4* vr = (const float4*)&v_lds[(t0 + i) * 32];
#pragma unroll
        for (int j = 0; j < 8; j++) {
            float4 vv = vr[j];
            part[4 * j + 0] += pv * vv.x;
            part[4 * j + 1] += pv * vv.y;
            part[4 * j + 2] += pv * vv.z;
            part[4 * j + 3] += pv * vv.w;
        }
    }
    int halfw = tid & 1;
    float outv[16];
#pragma unroll
    for (int d = 0; d < 32; d++) {
        float tot = part[d] + __shfl_xor(part[d], 1);
        if ((d >> 4) == halfw) outv[d & 15] = tot;
    }
    long obase = (long)(b * 128 + s) * 32 + hd * 8 + halfw * 4;
#pragma unroll
    for (int j = 0; j < 4; j++)
        ((float4*)o)[obase + j] = make_float4(outv[4 * j], outv[4 * j + 1], outv[4 * j + 2], outv[4 * j + 3]);
}

// ---------------------------------------------------------------------------
// mean-pool per graph + 3-layer MLP
// ---------------------------------------------------------------------------
__global__ __launch_bounds__(128) void pool_mlp_kernel(
    const float* __restrict__ h, const float* __restrict__ w1, const float* __restrict__ b1,
    const float* __restrict__ w2, const float* __restrict__ b2, const float* __restrict__ w3,
    const float* __restrict__ b3, float* __restrict__ out) {
    __shared__ float g[128], m1[64], m2[32];
    int b = blockIdx.x, tid = threadIdx.x;
    const float* hb = h + (long)b * 128 * 128;
    float s = 0.f;
    for (int r = 0; r < 128; r++) s += hb[r * 128 + tid];
    g[tid] = s * (1.f / 128.f);
    __syncthreads();
    if (tid < 64) {
        float a = b1[tid];
        for (int kk = 0; kk < 128; kk++) a += g[kk] * w1[kk * 64 + tid];
        m1[tid] = fmaxf(a, 0.f);
    }
    __syncthreads();
    if (tid < 32) {
        float a = b2[tid];
        for (int kk = 0; kk < 64; kk++) a += m1[kk] * w2[kk * 32 + tid];
        m2[tid] = fmaxf(a, 0.f);
    }
    __syncthreads();
    if (tid < 10) {
        float a = b3[tid];
        for (int kk = 0; kk < 32; kk++) a += m2[kk] * w3[kk * 10 + tid];
        out[b * 10 + tid] = a;
    }
}

// ---------------------------------------------------------------------------
extern "C" void kernel_launch(void* const* d_in, const int* in_sizes, int n_in,
                              void* d_out, int out_size, void* d_ws, size_t ws_size,
                              hipStream_t stream) {
    (void)in_sizes; (void)n_in; (void)out_size;
    const float* x        = (const float*)d_in[0];
    const float* pe       = (const float*)d_in[1];
    const float* edge_attr= (const float*)d_in[2];
    const float* sph      = (const float*)d_in[3];
    const float* node_w   = (const float*)d_in[4];
    const float* node_b   = (const float*)d_in[5];
    const float* pe_w     = (const float*)d_in[6];
    const float* pe_b     = (const float*)d_in[7];
    const float* conv_Aw  = (const float*)d_in[8];
    const float* conv_Ab  = (const float*)d_in[9];
    const float* conv_Bw  = (const float*)d_in[10];
    const float* conv_Bb  = (const float*)d_in[11];
    const float* conv_Cw  = (const float*)d_in[12];
    const float* conv_Cb  = (const float*)d_in[13];
    const float* conv_Dw  = (const float*)d_in[14];
    const float* conv_Db  = (const float*)d_in[15];
    const float* conv_Ew  = (const float*)d_in[16];
    const float* conv_Eb  = (const float*)d_in[17];
    const float* bnx_g    = (const float*)d_in[18];
    const float* bnx_b    = (const float*)d_in[19];
    const float* bne_g    = (const float*)d_in[20];
    const float* bne_b    = (const float*)d_in[21];
    const float* attn_w   = (const float*)d_in[22];
    const float* attn_b   = (const float*)d_in[23];
    const float* mlp1_w   = (const float*)d_in[24];
    const float* mlp1_b   = (const float*)d_in[25];
    const float* mlp2_w   = (const float*)d_in[26];
    const float* mlp2_b   = (const float*)d_in[27];
    const float* mlp3_w   = (const float*)d_in[28];
    const float* mlp3_b   = (const float*)d_in[29];
    const int*   eidx     = (const int*)d_in[30];
    const int* esrc = eidx;
    const int* edst = eidx + E_E;
    float* out = (float*)d_out;

    // workspace carve (floats first, then bf16 packs, then ints)
    float* f = (float*)d_ws;
    float* h      = f; f += (long)N_N * HID;
    float* hnew   = f; f += (long)N_N * HID;
    float* Ax     = f; f += (long)N_N * HID;   // q later
    float* Bx     = f; f += (long)N_N * HID;   // k later
    float* Dx     = f; f += (long)N_N * HID;   // v later
    float* Ex     = f; f += (long)N_N * HID;   // o later
    float* e      = f; f += (long)E_E * HID;
    float* eij    = f; f += (long)E_E * HID;
    float* partial= f; f += 512 * 256;
    float* bnxs   = f; f += 256;
    float* bnes   = f; f += 256;
    float* ebn_acc= f; f += STATS_REP * 256;
    __bf16* Whi = (__bf16*)f;           // 24 * 16384 bf16
    __bf16* Wlo = Whi + 24 * 16384;
    int* ip = (int*)(Wlo + 24 * 16384);
    int* deg     = ip; ip += N_N;
    int* row_ptr = ip; ip += N_N + 1;
    int* cursor  = ip; ip += N_N;
    int* perm    = ip; ip += E_E;
    int* ssrc    = ip; ip += E_E;
    int* sdst    = ip; ip += E_E;
    size_t need = (size_t)((char*)ip - (char*)d_ws);
    if (ws_size < need) return;  // out stays poisoned: signals ws too small

    // ---- pack all weight matrices (bf16 hi/lo, MFMA B-frag order) ----
    WSrc24 wsrc;
    for (int l = 0; l < L_LAYERS; l++) {
        wsrc.w[l * 5 + 0] = conv_Aw + l * 16384;
        wsrc.w[l * 5 + 1] = conv_Bw + l * 16384;
        wsrc.w[l * 5 + 2] = conv_Cw + l * 16384;
        wsrc.w[l * 5 + 3] = conv_Dw + l * 16384;
        wsrc.w[l * 5 + 4] = conv_Ew + l * 16384;
    }
    for (int m = 0; m < 4; m++) wsrc.w[20 + m] = attn_w + m * 16384;
    pack_w_kernel<<<96, 256, 0, stream>>>(wsrc, Whi, Wlo);

    // ---- build CSR by dst ----
    zero_int_kernel<<<(N_N + 255) / 256, 256, 0, stream>>>(deg, N_N);
    hist_kernel<<<E_E / 256, 256, 0, stream>>>(edst, deg);
    scan_kernel<<<1, 1024, 0, stream>>>(deg, row_ptr, cursor);
    scatter_kernel<<<E_E / 256, 256, 0, stream>>>(esrc, edst, cursor, perm, ssrc, sdst);

    embed_kernel<<<N_N * HID / 256, 256, 0, stream>>>(x, pe, node_w, node_b, pe_w, pe_b, h);

    for (int l = 0; l < L_LAYERS; l++) {
        zero_int_kernel<<<STATS_REP, 256, 0, stream>>>((int*)ebn_acc, STATS_REP * 256);

        // ABDE node GEMMs batched: y selects matrix (R3 config: 64 rows/block)
        Sel4 selN;
        selN.o[0] = Ax; selN.b[0] = conv_Ab + l * 128; selN.slot[0] = l * 5 + 0;
        selN.o[1] = Bx; selN.b[1] = conv_Bb + l * 128; selN.slot[1] = l * 5 + 1;
        selN.o[2] = Dx; selN.b[2] = conv_Db + l * 128; selN.slot[2] = l * 5 + 3;
        selN.o[3] = Ex; selN.b[3] = conv_Eb + l * 128; selN.slot[3] = l * 5 + 4;
        mfma_gemm_kernel<0><<<dim3(N_N / 64, 4), 256, 0, stream>>>(
            h, nullptr, Whi, Wlo, selN, nullptr, nullptr, nullptr, nullptr, nullptr);

        // edge GEMM: eij = e@Cw + Cb + Dx[dst] + Ex[src], fused BN stats
        const float* Asrc = (l == 0) ? edge_attr : e;
        const int* permA = (l == 0) ? perm : nullptr;
        Sel4 selE;
        selE.o[0] = eij; selE.b[0] = conv_Cb + l * 128; selE.slot[0] = l * 5 + 2;
        selE.o[1] = selE.o[2] = selE.o[3] = eij;
        selE.b[1] = selE.b[2] = selE.b[3] = selE.b[0];
        selE.slot[1] = selE.slot[2] = selE.slot[3] = selE.slot[0];
        mfma_gemm_kernel<1><<<dim3(E_E / 64, 1), 256, 0, stream>>>(
            Asrc, permA, Whi, Wlo, selE, Dx, Ex, sdst, ssrc, ebn_acc);

        ebn_finalize_kernel<<<1, 128, 0, stream>>>(ebn_acc, 1.f / E_E, bnes);

        // fused: aggregation (hnew) + edge BN/relu/residual (e update)
        const float* eoldSrc = (l == 0) ? edge_attr : e;
        const int* permE = (l == 0) ? perm : nullptr;
        agg_bn_kernel<<<N_N / 4, 256, 0, stream>>>(eij, Bx, Ax, row_ptr, ssrc, bnes,
                                                   bne_g + l * 128, bne_b + l * 128,
                                                   eoldSrc, permE, e, hnew);

        bn_stats_kernel<<<128, 256, 0, stream>>>(hnew, (long)N_N, partial);
        bn_finalize_kernel<<<1, 128, 0, stream>>>(partial, 128, 1.f / N_N, bnxs);
        bn_apply_res_kernel<<<N_N * 32 / 256, 256, 0, stream>>>(
            hnew, bnxs, bnx_g + l * 128, bnx_b + l * 128, h, (long)N_N * 32);

        // qkv batched: q=Ax, k=Bx, v=Dx
        Sel4 selQ;
        selQ.o[0] = Ax; selQ.b[0] = attn_b;       selQ.slot[0] = 20;
        selQ.o[1] = Bx; selQ.b[1] = attn_b + 128; selQ.slot[1] = 21;
        selQ.o[2] = Dx; selQ.b[2] = attn_b + 256; selQ.slot[2] = 22;
        selQ.o[3] = Dx; selQ.b[3] = attn_b + 256; selQ.slot[3] = 22;
        mfma_gemm_kernel<0><<<dim3(N_N / 64, 3), 256, 0, stream>>>(
            h, nullptr, Whi, Wlo, selQ, nullptr, nullptr, nullptr, nullptr, nullptr);

        attn_kernel<<<B_G * HEADS, 256, 0, stream>>>(Ax, Bx, Dx, sph, Ex);

        // output projection: h = o @ Wproj + b
        Sel4 selP;
        selP.o[0] = h; selP.b[0] = attn_b + 384; selP.slot[0] = 23;
        selP.o[1] = selP.o[2] = selP.o[3] = h;
        selP.b[1] = selP.b[2] = selP.b[3] = selP.b[0];
        selP.slot[1] = selP.slot[2] = selP.slot[3] = selP.slot[0];
        mfma_gemm_kernel<0><<<dim3(N_N / 64, 1), 256, 0, stream>>>(
            Ex, nullptr, Whi, Wlo, selP, nullptr, nullptr, nullptr, nullptr, nullptr);
    }

    pool_mlp_kernel<<<B_G, 128, 0, stream>>>(h, mlp1_w, mlp1_b, mlp2_w, mlp2_b, mlp3_w, mlp3_b, out);
}